// Round 3
// baseline (628.562 us; speedup 1.0000x reference)
//
#include <hip/hip_runtime.h>

// Problem constants (fixed by reference setup_inputs)
#define B   64
#define C   256
#define H   64
#define W   64
#define HW  (H * W)
#define KPT 21
#define CPARTS 4                 // channel-loop split factor
#define CPER   (C / CPARTS)      // 64 channels per part

// Native clang vector type — required for __builtin_nontemporal_load
// (HIP's float4 is a struct and is rejected by the builtin).
typedef float __attribute__((ext_vector_type(4))) fvec4;

// Kernel A: partial channel sums for both tensors.
// grid = dim3(256, CPARTS, 2): x = b*4 + pixel-chunk, y = channel part, z = tensor.
// 2048 blocks -> 8 blocks/CU, each thread does a 64-iteration fvec4 nontemporal
// read loop (16 KB stride), fully coalesced. Writes SUM over its 64 channels to
// parts[z][part][b][pix].
__global__ __launch_bounds__(256) void channel_sum_kernel(
    const float* __restrict__ f1, const float* __restrict__ f2,
    float* __restrict__ parts)
{
    const float* f = blockIdx.z ? f2 : f1;

    const int b    = blockIdx.x >> 2;                               // batch
    const int pix0 = ((blockIdx.x & 3) * 256 + threadIdx.x) * 4;    // pixel offset in [0,4096)
    const int c0   = blockIdx.y * CPER;

    const float* base = f + ((size_t)b * C + c0) * HW + pix0;

    fvec4 acc = (fvec4)(0.f);
    #pragma unroll 16
    for (int c = 0; c < CPER; ++c) {
        const fvec4 v = __builtin_nontemporal_load((const fvec4*)(base + (size_t)c * HW));
        acc += v;
    }

    float* out = parts + (((size_t)blockIdx.z * CPARTS + blockIdx.y) * B + b) * HW + pix0;
    *(fvec4*)out = acc;
}

// Kernel B: per-keypoint box means + batch mean.
// grid = 21 blocks (one per keypoint), 128 threads: wave 0 -> f1/pre1, wave 1 -> f2/pre2.
// lane = batch index (B == 64 == wavefront). Each lane sums its clamped box across the
// 4 channel-part planes (L2/L3-resident, 8 MB total), then 64-lane shuffle reduction.
__global__ __launch_bounds__(128) void box_mean_kernel(
    const float* __restrict__ parts,
    const int* __restrict__ pre1, const int* __restrict__ pre2,
    float* __restrict__ feas)   // feas[0..20] = fea_c1, feas[21..41] = fea_c2 (pre-momentum)
{
    const int k    = blockIdx.x;
    const int lane = threadIdx.x & 63;
    const int wave = threadIdx.x >> 6;
    const int b    = lane;

    const int* pre = wave ? pre2 : pre1;

    const int x = pre[(b * KPT + k) * 2 + 0];
    const int y = pre[(b * KPT + k) * 2 + 1];
    // torch slicing: rows from x bounds, cols from y bounds, exclusive upper.
    const int l = max(x - 6, 0);
    const int r = min(x + 6, 63);
    const int d = max(y - 6, 0);
    const int u = min(y + 6, 63);

    float s = 0.f;
    #pragma unroll
    for (int p = 0; p < CPARTS; ++p) {
        const float* base = parts + (((size_t)wave * CPARTS + p) * B + b) * HW;
        for (int row = l; row < r; ++row) {
            const float* rp = base + row * W;
            for (int col = d; col < u; ++col)
                s += rp[col];
        }
    }
    // s = sum over all 256 channels and box pixels; box mean of channel-mean map:
    float mean = s / ((float)((r - l) * (u - d)) * (float)C);

    // wave(64)-wide reduction: sum of box means over batch
    #pragma unroll
    for (int off = 32; off > 0; off >>= 1)
        mean += __shfl_down(mean, off, 64);

    if (lane == 0)
        feas[wave * KPT + k] = mean * (1.0f / (float)B);
}

// Kernel C: final MSE over 21 keypoints with momentum on fea_c2.
__global__ __launch_bounds__(64) void final_mse_kernel(
    const float* __restrict__ feas, float* __restrict__ out)
{
    const int k = threadIdx.x;
    float v = 0.f;
    if (k < KPT) {
        const float diff = feas[k] - 0.999f * feas[KPT + k];
        v = diff * diff;
    }
    #pragma unroll
    for (int off = 32; off > 0; off >>= 1)
        v += __shfl_down(v, off, 64);
    if (threadIdx.x == 0)
        out[0] = v * (1.0f / (float)KPT);
}

extern "C" void kernel_launch(void* const* d_in, const int* in_sizes, int n_in,
                              void* d_out, int out_size, void* d_ws, size_t ws_size,
                              hipStream_t stream)
{
    const float* f1  = (const float*)d_in[0];
    const float* f2  = (const float*)d_in[1];
    const int*  pre1 = (const int*)d_in[2];
    const int*  pre2 = (const int*)d_in[3];

    float* parts = (float*)d_ws;                         // 2 * 4 * 64 * 4096 floats = 8 MB
    float* feas  = parts + (size_t)2 * CPARTS * B * HW;  // 42 floats

    channel_sum_kernel<<<dim3(B * 4, CPARTS, 2), 256, 0, stream>>>(f1, f2, parts);
    box_mean_kernel<<<KPT, 128, 0, stream>>>(parts, pre1, pre2, feas);
    final_mse_kernel<<<1, 64, 0, stream>>>(feas, (float*)d_out);
}